// Round 1
// baseline (633.335 us; speedup 1.0000x reference)
//
#include <hip/hip_runtime.h>

#define IMG_H 512
#define IMG_W 512
#define OUT_H 510
#define OUT_W 510
#define NPLANE 48   // 16 batches * 3 channels
#define EPS 1e-6f

__global__ __launch_bounds__(256) void sobel_loss_kernel(
    const float* __restrict__ src, const float* __restrict__ tgt,
    float* __restrict__ out)
{
    const int x = blockIdx.x * blockDim.x + threadIdx.x;  // output col
    const int y = blockIdx.y;                              // output row
    const int p = blockIdx.z;                              // plane (b*c)

    float err = 0.0f;
    if (x < OUT_W) {
        const size_t base = (size_t)p * IMG_H * IMG_W + (size_t)y * IMG_W + x;
        const float* s = src + base;
        const float* t = tgt + base;

        // source 3x3 window
        float s00 = s[0],         s01 = s[1],         s02 = s[2];
        float s10 = s[IMG_W],     s11 = s[IMG_W + 1], s12 = s[IMG_W + 2];
        float s20 = s[2 * IMG_W], s21 = s[2 * IMG_W + 1], s22 = s[2 * IMG_W + 2];
        (void)s11;
        float gxs = (s00 - s02) + 2.0f * (s10 - s12) + (s20 - s22);
        float gys = (s00 + 2.0f * s01 + s02) - (s20 + 2.0f * s21 + s22);
        float ms = sqrtf(gxs * gxs + gys * gys);

        // target 3x3 window
        float t00 = t[0],         t01 = t[1],         t02 = t[2];
        float t10 = t[IMG_W],     t11 = t[IMG_W + 1], t12 = t[IMG_W + 2];
        float t20 = t[2 * IMG_W], t21 = t[2 * IMG_W + 1], t22 = t[2 * IMG_W + 2];
        (void)t11;
        float gxt = (t00 - t02) + 2.0f * (t10 - t12) + (t20 - t22);
        float gyt = (t00 + 2.0f * t01 + t02) - (t20 + 2.0f * t21 + t22);
        float mt = sqrtf(gxt * gxt + gyt * gyt);

        float d = ms - mt;
        err = sqrtf(d * d + EPS);
    }

    // wave(64) reduction
    #pragma unroll
    for (int off = 32; off > 0; off >>= 1)
        err += __shfl_down(err, off, 64);

    __shared__ float wsum[4];
    const int lane = threadIdx.x & 63;
    const int wid  = threadIdx.x >> 6;
    if (lane == 0) wsum[wid] = err;
    __syncthreads();
    if (threadIdx.x == 0) {
        float tot = wsum[0] + wsum[1] + wsum[2] + wsum[3];
        atomicAdd(out, tot * (1.0f / 16.0f));  // divide by batch B=16
    }
}

extern "C" void kernel_launch(void* const* d_in, const int* in_sizes, int n_in,
                              void* d_out, int out_size, void* d_ws, size_t ws_size,
                              hipStream_t stream) {
    const float* src = (const float*)d_in[0];
    const float* tgt = (const float*)d_in[1];
    float* out = (float*)d_out;

    // Harness poisons d_out once and does not re-poison between replays:
    // zero it every call so the atomic accumulation starts clean.
    hipMemsetAsync(out, 0, (size_t)out_size * sizeof(float), stream);

    dim3 block(256, 1, 1);
    dim3 grid((OUT_W + 255) / 256, OUT_H, NPLANE);
    sobel_loss_kernel<<<grid, block, 0, stream>>>(src, tgt, out);
}

// Round 2
// 67.824 us; speedup vs baseline: 9.3379x; 9.3379x over previous
//
#include <hip/hip_runtime.h>

#define IMG_H 512
#define IMG_W 512
#define OUT_H 510
#define OUT_W 510
#define NPLANE 48   // 16 batches * 3 channels
#define EPS 1e-6f
#define NBLOCKS 2048

__global__ __launch_bounds__(256) void sobel_loss_kernel(
    const float* __restrict__ src, const float* __restrict__ tgt,
    float* __restrict__ out)
{
    const int nrows = NPLANE * OUT_H;  // 24480 row-tasks
    float acc = 0.0f;

    for (int r = blockIdx.x; r < nrows; r += gridDim.x) {
        const int p = r / OUT_H;
        const int y = r - p * OUT_H;
        const size_t rowbase = (size_t)p * IMG_H * IMG_W + (size_t)y * IMG_W;

        for (int x = threadIdx.x; x < OUT_W; x += 256) {
            const float* s = src + rowbase + x;
            const float* t = tgt + rowbase + x;

            float s00 = s[0],         s01 = s[1],             s02 = s[2];
            float s10 = s[IMG_W],                             s12 = s[IMG_W + 2];
            float s20 = s[2 * IMG_W], s21 = s[2 * IMG_W + 1], s22 = s[2 * IMG_W + 2];
            float gxs = (s00 - s02) + 2.0f * (s10 - s12) + (s20 - s22);
            float gys = (s00 + 2.0f * s01 + s02) - (s20 + 2.0f * s21 + s22);
            float ms = sqrtf(gxs * gxs + gys * gys);

            float t00 = t[0],         t01 = t[1],             t02 = t[2];
            float t10 = t[IMG_W],                             t12 = t[IMG_W + 2];
            float t20 = t[2 * IMG_W], t21 = t[2 * IMG_W + 1], t22 = t[2 * IMG_W + 2];
            float gxt = (t00 - t02) + 2.0f * (t10 - t12) + (t20 - t22);
            float gyt = (t00 + 2.0f * t01 + t02) - (t20 + 2.0f * t21 + t22);
            float mt = sqrtf(gxt * gxt + gyt * gyt);

            float d = ms - mt;
            acc += sqrtf(d * d + EPS);
        }
    }

    // wave(64) butterfly reduction
    #pragma unroll
    for (int off = 32; off > 0; off >>= 1)
        acc += __shfl_down(acc, off, 64);

    __shared__ float wsum[4];
    const int lane = threadIdx.x & 63;
    const int wid  = threadIdx.x >> 6;
    if (lane == 0) wsum[wid] = acc;
    __syncthreads();
    if (threadIdx.x == 0) {
        float tot = wsum[0] + wsum[1] + wsum[2] + wsum[3];
        atomicAdd(out, tot * (1.0f / 16.0f));  // divide by batch B=16
    }
}

extern "C" void kernel_launch(void* const* d_in, const int* in_sizes, int n_in,
                              void* d_out, int out_size, void* d_ws, size_t ws_size,
                              hipStream_t stream) {
    const float* src = (const float*)d_in[0];
    const float* tgt = (const float*)d_in[1];
    float* out = (float*)d_out;

    // Harness poisons d_out once and does not re-poison between replays:
    // zero it every call so the atomic accumulation starts clean.
    hipMemsetAsync(out, 0, (size_t)out_size * sizeof(float), stream);

    dim3 block(256, 1, 1);
    dim3 grid(NBLOCKS, 1, 1);
    sobel_loss_kernel<<<grid, block, 0, stream>>>(src, tgt, out);
}

// Round 3
// 44.497 us; speedup vs baseline: 14.2331x; 1.5242x over previous
//
#include <hip/hip_runtime.h>

#define IMG_W 512
#define IMG_H 512
#define OUT_W 510
#define OUT_H 510
#define NPLANE 48            // 16 batches * 3 channels
#define STRIP 10             // output rows per block-strip (510 = 10*51)
#define SPP (OUT_H / STRIP)  // 51 strips per plane
#define NB (NPLANE * SPP)    // 2448 blocks
#define EPS 1e-6f

struct Row { float v[8]; };

__device__ __forceinline__ void load_row(Row& r, const float* p, int off2) {
    float4 v0 = *reinterpret_cast<const float4*>(p);
    float4 v1 = *reinterpret_cast<const float4*>(p + off2);
    r.v[0] = v0.x; r.v[1] = v0.y; r.v[2] = v0.z; r.v[3] = v0.w;
    r.v[4] = v1.x; r.v[5] = v1.y; r.v[6] = v1.z; r.v[7] = v1.w;
}

// Each block: one (plane, 10-row strip). 128 threads, each owns 4 output cols.
// Rolling 3-row register window, prefetch next row one iteration ahead.
template <bool ATOMIC>
__global__ __launch_bounds__(128) void sobel_partial_kernel(
    const float* __restrict__ src, const float* __restrict__ tgt,
    float* __restrict__ partial)
{
    const int cid = threadIdx.x;            // 0..127
    const int x   = cid * 4;                // first output col (aligned 16B)
    // last tile (x=508): 2nd float4 would read past row/buffer; its data only
    // feeds masked-out outputs 510,511 — clamp the address instead of loading OOB.
    const int off2 = (x + 4 < IMG_W) ? 4 : 0;

    const int s  = blockIdx.x;
    const int p  = s / SPP;
    const int ys = (s - p * SPP) * STRIP;

    const float* sp = src + (size_t)p * IMG_W * IMG_H + (size_t)ys * IMG_W + x;
    const float* tp = tgt + (size_t)p * IMG_W * IMG_H + (size_t)ys * IMG_W + x;

    Row sa, sb, sc, ta, tb, tc;
    load_row(sa, sp, off2);
    load_row(sb, sp + IMG_W, off2);
    load_row(sc, sp + 2 * IMG_W, off2);
    load_row(ta, tp, off2);
    load_row(tb, tp + IMG_W, off2);
    load_row(tc, tp + 2 * IMG_W, off2);

    float acc = 0.0f;

    #pragma unroll 2
    for (int i = 0; i < STRIP; ++i) {
        Row sn, tn;
        if (i < STRIP - 1) {                 // prefetch row ys+i+3 (uniform branch)
            load_row(sn, sp + (size_t)(i + 3) * IMG_W, off2);
            load_row(tn, tp + (size_t)(i + 3) * IMG_W, off2);
        }

        #pragma unroll
        for (int j = 0; j < 4; ++j) {
            float gxs = (sa.v[j] - sa.v[j + 2]) + 2.0f * (sb.v[j] - sb.v[j + 2]) + (sc.v[j] - sc.v[j + 2]);
            float gys = (sa.v[j] + 2.0f * sa.v[j + 1] + sa.v[j + 2])
                      - (sc.v[j] + 2.0f * sc.v[j + 1] + sc.v[j + 2]);
            float ms = sqrtf(gxs * gxs + gys * gys);

            float gxt = (ta.v[j] - ta.v[j + 2]) + 2.0f * (tb.v[j] - tb.v[j + 2]) + (tc.v[j] - tc.v[j + 2]);
            float gyt = (ta.v[j] + 2.0f * ta.v[j + 1] + ta.v[j + 2])
                      - (tc.v[j] + 2.0f * tc.v[j + 1] + tc.v[j + 2]);
            float mt = sqrtf(gxt * gxt + gyt * gyt);

            float d = ms - mt;
            if (x + j < OUT_W) acc += sqrtf(d * d + EPS);
        }

        sa = sb; sb = sc; sc = sn;
        ta = tb; tb = tc; tc = tn;
    }

    // block reduction: 2 waves
    #pragma unroll
    for (int off = 32; off > 0; off >>= 1)
        acc += __shfl_down(acc, off, 64);

    __shared__ float wsum[2];
    const int lane = threadIdx.x & 63;
    const int wid  = threadIdx.x >> 6;
    if (lane == 0) wsum[wid] = acc;
    __syncthreads();
    if (threadIdx.x == 0) {
        float tot = wsum[0] + wsum[1];
        if (ATOMIC) atomicAdd(partial, tot * (1.0f / 16.0f));
        else        partial[blockIdx.x] = tot;
    }
}

__global__ __launch_bounds__(256) void reduce_kernel(
    const float* __restrict__ partial, float* __restrict__ out)
{
    float acc = 0.0f;
    for (int i = threadIdx.x; i < NB; i += 256) acc += partial[i];

    #pragma unroll
    for (int off = 32; off > 0; off >>= 1)
        acc += __shfl_down(acc, off, 64);

    __shared__ float wsum[4];
    const int lane = threadIdx.x & 63;
    const int wid  = threadIdx.x >> 6;
    if (lane == 0) wsum[wid] = acc;
    __syncthreads();
    if (threadIdx.x == 0)
        out[0] = (wsum[0] + wsum[1] + wsum[2] + wsum[3]) * (1.0f / 16.0f);
}

extern "C" void kernel_launch(void* const* d_in, const int* in_sizes, int n_in,
                              void* d_out, int out_size, void* d_ws, size_t ws_size,
                              hipStream_t stream) {
    const float* src = (const float*)d_in[0];
    const float* tgt = (const float*)d_in[1];
    float* out = (float*)d_out;

    if (ws_size >= (size_t)NB * sizeof(float)) {
        float* partial = (float*)d_ws;
        sobel_partial_kernel<false><<<dim3(NB), dim3(128), 0, stream>>>(src, tgt, partial);
        reduce_kernel<<<dim3(1), dim3(256), 0, stream>>>(partial, out);
    } else {
        // fallback: atomic accumulation directly into out
        hipMemsetAsync(out, 0, (size_t)out_size * sizeof(float), stream);
        sobel_partial_kernel<true><<<dim3(NB), dim3(128), 0, stream>>>(src, tgt, out);
    }
}

// Round 4
// 40.762 us; speedup vs baseline: 15.5374x; 1.0916x over previous
//
#include <hip/hip_runtime.h>

#define IMG_W 512
#define IMG_H 512
#define OUT_W 510
#define OUT_H 510
#define NPLANE 48            // 16 batches * 3 channels
#define STRIP 10             // output rows per block-strip (510 = 10*51)
#define SPP (OUT_H / STRIP)  // 51 strips per plane
#define NB (NPLANE * SPP)    // 2448 blocks
#define EPS 1e-6f

// Each block: one (plane, 10-row strip). 128 threads, each owns 4 output cols.
// Per input row compute horizontal prefactors once:
//   hd[j] = v[j] - v[j+2]          (feeds gx of 3 output rows)
//   hs[j] = v[j] + 2v[j+1] + v[j+2] (feeds gy of 3 output rows)
// 4-slot modular window, strip loop fully unrolled -> static indices, no movs.
template <bool ATOMIC>
__global__ __launch_bounds__(128) void sobel_partial_kernel(
    const float* __restrict__ src, const float* __restrict__ tgt,
    float* __restrict__ partial)
{
    const int tid = threadIdx.x;           // 0..127
    const int x   = tid * 4;               // first output col, 16B aligned
    // thread 127: cols 510/511 are masked; clamp the float2 so it never
    // reads past the buffer (its values only feed masked outputs).
    const int off2 = (x + 4 < IMG_W) ? 4 : 0;

    float msk[4];
    #pragma unroll
    for (int j = 0; j < 4; ++j) msk[j] = (x + j < OUT_W) ? 1.0f : 0.0f;

    const int s  = blockIdx.x;
    const int p  = s / SPP;
    const int ys = (s - p * SPP) * STRIP;

    const float* sp = src + (size_t)p * IMG_W * IMG_H + (size_t)ys * IMG_W + x;
    const float* tp = tgt + (size_t)p * IMG_W * IMG_H + (size_t)ys * IMG_W + x;

    float hd_s[4][4], hs_s[4][4], hd_t[4][4], hs_t[4][4];

    auto loadrow = [&](const float* base, int r, float hd[4], float hs[4]) {
        const float* q = base + (size_t)r * IMG_W;
        float4 a  = *reinterpret_cast<const float4*>(q);
        float2 b  = *reinterpret_cast<const float2*>(q + off2);
        float v4 = b.x, v5 = b.y;
        hd[0] = a.x - a.z;
        hd[1] = a.y - a.w;
        hd[2] = a.z - v4;
        hd[3] = a.w - v5;
        hs[0] = fmaf(2.0f, a.y, a.x + a.z);
        hs[1] = fmaf(2.0f, a.z, a.y + a.w);
        hs[2] = fmaf(2.0f, a.w, a.z + v4);
        hs[3] = fmaf(2.0f, v4,  a.w + v5);
    };

    // preload rows 0,1,2 into slots 0,1,2
    #pragma unroll
    for (int r = 0; r < 3; ++r) {
        loadrow(sp, r, hd_s[r], hs_s[r]);
        loadrow(tp, r, hd_t[r], hs_t[r]);
    }

    float acc = 0.0f;

    #pragma unroll
    for (int i = 0; i < STRIP; ++i) {
        if (i < STRIP - 1) {               // prefetch input row i+3
            const int sl = (i + 3) & 3;
            loadrow(sp, i + 3, hd_s[sl], hs_s[sl]);
            loadrow(tp, i + 3, hd_t[sl], hs_t[sl]);
        }
        const int ca = i & 3, cb = (i + 1) & 3, cc = (i + 2) & 3;

        #pragma unroll
        for (int j = 0; j < 4; ++j) {
            float gxs = fmaf(2.0f, hd_s[cb][j], hd_s[ca][j] + hd_s[cc][j]);
            float gys = hs_s[ca][j] - hs_s[cc][j];
            float ms  = sqrtf(fmaf(gxs, gxs, gys * gys));

            float gxt = fmaf(2.0f, hd_t[cb][j], hd_t[ca][j] + hd_t[cc][j]);
            float gyt = hs_t[ca][j] - hs_t[cc][j];
            float mt  = sqrtf(fmaf(gxt, gxt, gyt * gyt));

            float d = ms - mt;
            float e = sqrtf(fmaf(d, d, EPS));
            acc = fmaf(e, msk[j], acc);
        }
    }

    // block reduction: 2 waves
    #pragma unroll
    for (int off = 32; off > 0; off >>= 1)
        acc += __shfl_down(acc, off, 64);

    __shared__ float wsum[2];
    const int lane = threadIdx.x & 63;
    const int wid  = threadIdx.x >> 6;
    if (lane == 0) wsum[wid] = acc;
    __syncthreads();
    if (threadIdx.x == 0) {
        float tot = wsum[0] + wsum[1];
        if (ATOMIC) atomicAdd(partial, tot * (1.0f / 16.0f));
        else        partial[blockIdx.x] = tot;
    }
}

__global__ __launch_bounds__(256) void reduce_kernel(
    const float* __restrict__ partial, float* __restrict__ out)
{
    float acc = 0.0f;
    for (int i = threadIdx.x; i < NB; i += 256) acc += partial[i];

    #pragma unroll
    for (int off = 32; off > 0; off >>= 1)
        acc += __shfl_down(acc, off, 64);

    __shared__ float wsum[4];
    const int lane = threadIdx.x & 63;
    const int wid  = threadIdx.x >> 6;
    if (lane == 0) wsum[wid] = acc;
    __syncthreads();
    if (threadIdx.x == 0)
        out[0] = (wsum[0] + wsum[1] + wsum[2] + wsum[3]) * (1.0f / 16.0f);
}

extern "C" void kernel_launch(void* const* d_in, const int* in_sizes, int n_in,
                              void* d_out, int out_size, void* d_ws, size_t ws_size,
                              hipStream_t stream) {
    const float* src = (const float*)d_in[0];
    const float* tgt = (const float*)d_in[1];
    float* out = (float*)d_out;

    if (ws_size >= (size_t)NB * sizeof(float)) {
        float* partial = (float*)d_ws;
        sobel_partial_kernel<false><<<dim3(NB), dim3(128), 0, stream>>>(src, tgt, partial);
        reduce_kernel<<<dim3(1), dim3(256), 0, stream>>>(partial, out);
    } else {
        hipMemsetAsync(out, 0, (size_t)out_size * sizeof(float), stream);
        sobel_partial_kernel<true><<<dim3(NB), dim3(128), 0, stream>>>(src, tgt, out);
    }
}

// Round 5
// 35.059 us; speedup vs baseline: 18.0646x; 1.1627x over previous
//
#include <hip/hip_runtime.h>

#define IMG_W 512
#define IMG_H 512
#define OUT_W 510
#define OUT_H 510
#define NPLANE 48            // 16 batches * 3 channels
#define STRIP 6              // output rows per block-strip (510 = 6*85)
#define SPP (OUT_H / STRIP)  // 85 strips per plane
#define NB (NPLANE * SPP)    // 4080 blocks
#define EPS 1e-6f

// Per block: one (plane, 6-row strip). 128 threads, each owns 4 output cols.
// Software pipeline (all loops fully unrolled, %3 indices are compile-time):
//   iter i: issue raw loads for input row i+4 (2 iters ahead of conversion)
//           convert raw row i+2 -> horizontal prefactors (1 iter ahead of last use)
//           compute output row i from prefactor rows i, i+1, i+2
// Prefactors per input row (computed once, used by 3 output rows):
//   hd[j] = v[j] - v[j+2]; hs[j] = v[j] + 2v[j+1] + v[j+2]
struct Raw { float v[6]; };

template <bool ATOMIC>
__global__ __launch_bounds__(128) void sobel_partial_kernel(
    const float* __restrict__ src, const float* __restrict__ tgt,
    float* __restrict__ partial)
{
    const int tid = threadIdx.x;           // 0..127
    const int x   = tid * 4;               // first output col, 16B aligned
    // thread 127: cols 510/511 masked; clamp the float2 so it never reads OOB
    const int off2 = (x + 4 < IMG_W) ? 4 : 0;

    float msk[4];
    #pragma unroll
    for (int j = 0; j < 4; ++j) msk[j] = (x + j < OUT_W) ? 1.0f : 0.0f;

    const int s  = blockIdx.x;
    const int p  = s / SPP;
    const int ys = (s - p * SPP) * STRIP;

    const float* sp = src + (size_t)p * IMG_W * IMG_H + (size_t)ys * IMG_W + x;
    const float* tp = tgt + (size_t)p * IMG_W * IMG_H + (size_t)ys * IMG_W + x;

    Raw rawS[3], rawT[3];
    float hdS[3][4], hsS[3][4], hdT[3][4], hsT[3][4];

    auto loadraw = [&](const float* base, int r, Raw& rw) {
        const float* q = base + (size_t)r * IMG_W;
        float4 a = *reinterpret_cast<const float4*>(q);
        float2 b = *reinterpret_cast<const float2*>(q + off2);
        rw.v[0] = a.x; rw.v[1] = a.y; rw.v[2] = a.z; rw.v[3] = a.w;
        rw.v[4] = b.x; rw.v[5] = b.y;
    };
    auto convert = [&](const Raw& rw, float hd[4], float hs[4]) {
        hd[0] = rw.v[0] - rw.v[2];
        hd[1] = rw.v[1] - rw.v[3];
        hd[2] = rw.v[2] - rw.v[4];
        hd[3] = rw.v[3] - rw.v[5];
        hs[0] = fmaf(2.0f, rw.v[1], rw.v[0] + rw.v[2]);
        hs[1] = fmaf(2.0f, rw.v[2], rw.v[1] + rw.v[3]);
        hs[2] = fmaf(2.0f, rw.v[3], rw.v[2] + rw.v[4]);
        hs[3] = fmaf(2.0f, rw.v[4], rw.v[3] + rw.v[5]);
    };

    // prologue: issue loads for rows 0,1,2; convert rows 0,1
    #pragma unroll
    for (int r = 0; r < 3; ++r) {
        loadraw(sp, r, rawS[r]);
        loadraw(tp, r, rawT[r]);
    }
    #pragma unroll
    for (int r = 0; r < 2; ++r) {
        convert(rawS[r], hdS[r], hsS[r]);
        convert(rawT[r], hdT[r], hsT[r]);
    }

    float acc = 0.0f;

    #pragma unroll
    for (int i = 0; i < STRIP; ++i) {
        // issue loads for row i+4 (overwrites slot of row i+1, already converted)
        if (i + 4 < STRIP + 2) {
            const int sl = (i + 4) % 3;
            loadraw(sp, i + 4, rawS[sl]);
            loadraw(tp, i + 4, rawT[sl]);
        }
        // convert row i+2 (loaded 2 iters ago)
        {
            const int sl = (i + 2) % 3;
            convert(rawS[sl], hdS[sl], hsS[sl]);
            convert(rawT[sl], hdT[sl], hsT[sl]);
        }
        const int ca = i % 3, cb = (i + 1) % 3, cc = (i + 2) % 3;

        #pragma unroll
        for (int j = 0; j < 4; ++j) {
            float gxs = fmaf(2.0f, hdS[cb][j], hdS[ca][j] + hdS[cc][j]);
            float gys = hsS[ca][j] - hsS[cc][j];
            float ms  = sqrtf(fmaf(gxs, gxs, gys * gys));

            float gxt = fmaf(2.0f, hdT[cb][j], hdT[ca][j] + hdT[cc][j]);
            float gyt = hsT[ca][j] - hsT[cc][j];
            float mt  = sqrtf(fmaf(gxt, gxt, gyt * gyt));

            float d = ms - mt;
            float e = sqrtf(fmaf(d, d, EPS));
            acc = fmaf(e, msk[j], acc);
        }
    }

    // block reduction: 2 waves
    #pragma unroll
    for (int off = 32; off > 0; off >>= 1)
        acc += __shfl_down(acc, off, 64);

    __shared__ float wsum[2];
    const int lane = threadIdx.x & 63;
    const int wid  = threadIdx.x >> 6;
    if (lane == 0) wsum[wid] = acc;
    __syncthreads();
    if (threadIdx.x == 0) {
        float tot = wsum[0] + wsum[1];
        if (ATOMIC) atomicAdd(partial, tot * (1.0f / 16.0f));
        else        partial[blockIdx.x] = tot;
    }
}

__global__ __launch_bounds__(256) void reduce_kernel(
    const float* __restrict__ partial, float* __restrict__ out)
{
    float acc = 0.0f;
    for (int i = threadIdx.x; i < NB; i += 256) acc += partial[i];

    #pragma unroll
    for (int off = 32; off > 0; off >>= 1)
        acc += __shfl_down(acc, off, 64);

    __shared__ float wsum[4];
    const int lane = threadIdx.x & 63;
    const int wid  = threadIdx.x >> 6;
    if (lane == 0) wsum[wid] = acc;
    __syncthreads();
    if (threadIdx.x == 0)
        out[0] = (wsum[0] + wsum[1] + wsum[2] + wsum[3]) * (1.0f / 16.0f);
}

extern "C" void kernel_launch(void* const* d_in, const int* in_sizes, int n_in,
                              void* d_out, int out_size, void* d_ws, size_t ws_size,
                              hipStream_t stream) {
    const float* src = (const float*)d_in[0];
    const float* tgt = (const float*)d_in[1];
    float* out = (float*)d_out;

    if (ws_size >= (size_t)NB * sizeof(float)) {
        float* partial = (float*)d_ws;
        sobel_partial_kernel<false><<<dim3(NB), dim3(128), 0, stream>>>(src, tgt, partial);
        reduce_kernel<<<dim3(1), dim3(256), 0, stream>>>(partial, out);
    } else {
        hipMemsetAsync(out, 0, (size_t)out_size * sizeof(float), stream);
        sobel_partial_kernel<true><<<dim3(NB), dim3(128), 0, stream>>>(src, tgt, out);
    }
}

// Round 6
// 34.129 us; speedup vs baseline: 18.5573x; 1.0273x over previous
//
#include <hip/hip_runtime.h>

#define IMG_W 512
#define IMG_H 512
#define OUT_W 510
#define OUT_H 510
#define NPLANE 48            // 16 batches * 3 channels
#define STRIP 5              // output rows per block-strip (510 = 5*102)
#define SPP (OUT_H / STRIP)  // 102 strips per plane
#define NB (NPLANE * SPP)    // 4896 blocks
#define NROWS (STRIP + 2)    // 7 input rows per block
#define EPS 1e-6f

struct Raw { float v[6]; };

// Per block: one (plane, 5-row strip). 128 threads, each owns 4 output cols.
// ALL loads (7 rows x 2 images x {float4,float2}) are issued at block start
// and stay in flight; compute consumes rows in order (compiler inserts
// vmcnt(N) waits). No prefactor arrays: horizontal terms are recomputed per
// output row -- more VALU (cheap, we're latency-bound) for fewer VGPRs.
template <bool ATOMIC>
__global__ __launch_bounds__(128) void sobel_partial_kernel(
    const float* __restrict__ src, const float* __restrict__ tgt,
    float* __restrict__ partial)
{
    const int tid = threadIdx.x;           // 0..127
    const int x   = tid * 4;               // first output col, 16B aligned
    // thread 127: cols 510/511 masked; clamp the float2 so it never reads OOB
    const int off2 = (x + 4 < IMG_W) ? 4 : 0;

    float msk[4];
    #pragma unroll
    for (int j = 0; j < 4; ++j) msk[j] = (x + j < OUT_W) ? 1.0f : 0.0f;

    const int s  = blockIdx.x;
    const int p  = s / SPP;
    const int ys = (s - p * SPP) * STRIP;

    const float* sp = src + (size_t)p * IMG_W * IMG_H + (size_t)ys * IMG_W + x;
    const float* tp = tgt + (size_t)p * IMG_W * IMG_H + (size_t)ys * IMG_W + x;

    Raw rS[NROWS], rT[NROWS];

    #pragma unroll
    for (int r = 0; r < NROWS; ++r) {
        const float* qs = sp + (size_t)r * IMG_W;
        float4 a = *reinterpret_cast<const float4*>(qs);
        float2 b = *reinterpret_cast<const float2*>(qs + off2);
        rS[r].v[0] = a.x; rS[r].v[1] = a.y; rS[r].v[2] = a.z;
        rS[r].v[3] = a.w; rS[r].v[4] = b.x; rS[r].v[5] = b.y;
        const float* qt = tp + (size_t)r * IMG_W;
        float4 c = *reinterpret_cast<const float4*>(qt);
        float2 d = *reinterpret_cast<const float2*>(qt + off2);
        rT[r].v[0] = c.x; rT[r].v[1] = c.y; rT[r].v[2] = c.z;
        rT[r].v[3] = c.w; rT[r].v[4] = d.x; rT[r].v[5] = d.y;
    }

    float acc = 0.0f;

    #pragma unroll
    for (int i = 0; i < STRIP; ++i) {
        const Raw& sa = rS[i]; const Raw& sb = rS[i + 1]; const Raw& sc = rS[i + 2];
        const Raw& ta = rT[i]; const Raw& tb = rT[i + 1]; const Raw& tc = rT[i + 2];

        #pragma unroll
        for (int j = 0; j < 4; ++j) {
            float gxs = fmaf(2.0f, sb.v[j] - sb.v[j + 2],
                             (sa.v[j] - sa.v[j + 2]) + (sc.v[j] - sc.v[j + 2]));
            float gys = fmaf(2.0f, sa.v[j + 1], sa.v[j] + sa.v[j + 2])
                      - fmaf(2.0f, sc.v[j + 1], sc.v[j] + sc.v[j + 2]);
            float ms  = sqrtf(fmaf(gxs, gxs, gys * gys));

            float gxt = fmaf(2.0f, tb.v[j] - tb.v[j + 2],
                             (ta.v[j] - ta.v[j + 2]) + (tc.v[j] - tc.v[j + 2]));
            float gyt = fmaf(2.0f, ta.v[j + 1], ta.v[j] + ta.v[j + 2])
                      - fmaf(2.0f, tc.v[j + 1], tc.v[j] + tc.v[j + 2]);
            float mt  = sqrtf(fmaf(gxt, gxt, gyt * gyt));

            float d = ms - mt;
            float e = sqrtf(fmaf(d, d, EPS));
            acc = fmaf(e, msk[j], acc);
        }
    }

    // block reduction: 2 waves
    #pragma unroll
    for (int off = 32; off > 0; off >>= 1)
        acc += __shfl_down(acc, off, 64);

    __shared__ float wsum[2];
    const int lane = threadIdx.x & 63;
    const int wid  = threadIdx.x >> 6;
    if (lane == 0) wsum[wid] = acc;
    __syncthreads();
    if (threadIdx.x == 0) {
        float tot = wsum[0] + wsum[1];
        if (ATOMIC) atomicAdd(partial, tot * (1.0f / 16.0f));
        else        partial[blockIdx.x] = tot;
    }
}

__global__ __launch_bounds__(1024) void reduce_kernel(
    const float* __restrict__ partial, float* __restrict__ out)
{
    float acc = 0.0f;
    for (int i = threadIdx.x; i < NB; i += 1024) acc += partial[i];

    #pragma unroll
    for (int off = 32; off > 0; off >>= 1)
        acc += __shfl_down(acc, off, 64);

    __shared__ float wsum[16];
    const int lane = threadIdx.x & 63;
    const int wid  = threadIdx.x >> 6;
    if (lane == 0) wsum[wid] = acc;
    __syncthreads();
    if (wid == 0) {
        float v = (lane < 16) ? wsum[lane] : 0.0f;
        #pragma unroll
        for (int off = 8; off > 0; off >>= 1)
            v += __shfl_down(v, off, 64);
        if (lane == 0) out[0] = v * (1.0f / 16.0f);
    }
}

extern "C" void kernel_launch(void* const* d_in, const int* in_sizes, int n_in,
                              void* d_out, int out_size, void* d_ws, size_t ws_size,
                              hipStream_t stream) {
    const float* src = (const float*)d_in[0];
    const float* tgt = (const float*)d_in[1];
    float* out = (float*)d_out;

    if (ws_size >= (size_t)NB * sizeof(float)) {
        float* partial = (float*)d_ws;
        sobel_partial_kernel<false><<<dim3(NB), dim3(128), 0, stream>>>(src, tgt, partial);
        reduce_kernel<<<dim3(1), dim3(1024), 0, stream>>>(partial, out);
    } else {
        hipMemsetAsync(out, 0, (size_t)out_size * sizeof(float), stream);
        sobel_partial_kernel<true><<<dim3(NB), dim3(128), 0, stream>>>(src, tgt, out);
    }
}

// Round 7
// 26.406 us; speedup vs baseline: 23.9843x; 1.2925x over previous
//
#include <hip/hip_runtime.h>

#define IMG_W 512
#define IMG_H 512
#define OUT_W 510
#define OUT_H 510
#define NPLANE 48                      // 16 batches * 3 channels
#define RPW 3                          // output rows per wave
#define WPB 4                          // waves per block (256 threads)
#define RPB (RPW * WPB)                // 12 output rows per block
#define SPP ((OUT_H + RPB - 1) / RPB)  // 43 strips per plane (516 rows, tail masked)
#define NB (NPLANE * SPP)              // 2064 blocks
#define NWIN (RPW + 2)                 // 5 input rows per wave
#define EPS 1e-6f

// Wave-per-row decomposition: 64 lanes x 8 cols = 512 = full image width.
// Each lane loads exactly its 32B of a row (2 x float4, no overlap); the
// 2-col horizontal halo comes from __shfl_down(.,1). All 20 loads issued
// up-front; waves are sync-free until the final block reduction.
template <bool ATOMIC>
__global__ __launch_bounds__(256) void sobel_partial_kernel(
    const float* __restrict__ src, const float* __restrict__ tgt,
    float* __restrict__ partial)
{
    const int tid  = threadIdx.x;
    const int lane = tid & 63;
    const int wv   = tid >> 6;          // 0..3
    const int xb   = lane * 8;          // lane's first column

    const int s  = blockIdx.x;
    const int p  = s / SPP;
    const int y0 = (s - p * SPP) * RPB + wv * RPW;  // wave's first output row

    const float* ps = src + (size_t)p * IMG_W * IMG_H + xb;
    const float* pt = tgt + (size_t)p * IMG_W * IMG_H + xb;

    float vS[NWIN][8], vT[NWIN][8];
    #pragma unroll
    for (int r = 0; r < NWIN; ++r) {
        int ir = y0 + r;                 // clamp: tail-strip rows are masked out
        if (ir > IMG_H - 1) ir = IMG_H - 1;
        const float* qs = ps + (size_t)ir * IMG_W;
        float4 a = *reinterpret_cast<const float4*>(qs);
        float4 b = *reinterpret_cast<const float4*>(qs + 4);
        vS[r][0] = a.x; vS[r][1] = a.y; vS[r][2] = a.z; vS[r][3] = a.w;
        vS[r][4] = b.x; vS[r][5] = b.y; vS[r][6] = b.z; vS[r][7] = b.w;
        const float* qt = pt + (size_t)ir * IMG_W;
        float4 c = *reinterpret_cast<const float4*>(qt);
        float4 d = *reinterpret_cast<const float4*>(qt + 4);
        vT[r][0] = c.x; vT[r][1] = c.y; vT[r][2] = c.z; vT[r][3] = c.w;
        vT[r][4] = d.x; vT[r][5] = d.y; vT[r][6] = d.z; vT[r][7] = d.w;
    }

    float e0S[NWIN], e1S[NWIN], e0T[NWIN], e1T[NWIN];
    auto halo = [&](int r) {
        e0S[r] = __shfl_down(vS[r][0], 1, 64);   // col xb+8
        e1S[r] = __shfl_down(vS[r][1], 1, 64);   // col xb+9
        e0T[r] = __shfl_down(vT[r][0], 1, 64);
        e1T[r] = __shfl_down(vT[r][1], 1, 64);
    };
    // lane 63 gets garbage halo, but it only feeds cols 510/511 -> masked.

    auto VS = [&](int r, int k) -> float {
        return k < 8 ? vS[r][k] : (k == 8 ? e0S[r] : e1S[r]);
    };
    auto VT = [&](int r, int k) -> float {
        return k < 8 ? vT[r][k] : (k == 8 ? e0T[r] : e1T[r]);
    };

    float cm[8];
    #pragma unroll
    for (int j = 0; j < 8; ++j) cm[j] = (xb + j < OUT_W) ? 1.0f : 0.0f;

    float acc = 0.0f;

    #pragma unroll
    for (int i = 0; i < RPW; ++i) {
        if (i == 0) { halo(0); halo(1); halo(2); }
        else        { halo(i + 2); }

        const int a = i, b = i + 1, c = i + 2;
        float rowsum = 0.0f;

        #pragma unroll
        for (int j = 0; j < 8; ++j) {
            float gxs = fmaf(2.0f, VS(b, j) - VS(b, j + 2),
                             (VS(a, j) - VS(a, j + 2)) + (VS(c, j) - VS(c, j + 2)));
            float gys = fmaf(2.0f, VS(a, j + 1), VS(a, j) + VS(a, j + 2))
                      - fmaf(2.0f, VS(c, j + 1), VS(c, j) + VS(c, j + 2));
            float ms  = __builtin_amdgcn_sqrtf(fmaf(gxs, gxs, gys * gys));

            float gxt = fmaf(2.0f, VT(b, j) - VT(b, j + 2),
                             (VT(a, j) - VT(a, j + 2)) + (VT(c, j) - VT(c, j + 2)));
            float gyt = fmaf(2.0f, VT(a, j + 1), VT(a, j) + VT(a, j + 2))
                      - fmaf(2.0f, VT(c, j + 1), VT(c, j) + VT(c, j + 2));
            float mt  = __builtin_amdgcn_sqrtf(fmaf(gxt, gxt, gyt * gyt));

            float d2 = ms - mt;
            float e  = __builtin_amdgcn_sqrtf(fmaf(d2, d2, EPS));
            rowsum = fmaf(e, cm[j], rowsum);
        }

        float rm = (y0 + i < OUT_H) ? 1.0f : 0.0f;  // tail-strip row mask
        acc = fmaf(rowsum, rm, acc);
    }

    // block reduction: 4 waves
    #pragma unroll
    for (int off = 32; off > 0; off >>= 1)
        acc += __shfl_down(acc, off, 64);

    __shared__ float wsum[WPB];
    if (lane == 0) wsum[wv] = acc;
    __syncthreads();
    if (tid == 0) {
        float tot = wsum[0] + wsum[1] + wsum[2] + wsum[3];
        if (ATOMIC) atomicAdd(partial, tot * (1.0f / 16.0f));
        else        partial[blockIdx.x] = tot;
    }
}

__global__ __launch_bounds__(1024) void reduce_kernel(
    const float* __restrict__ partial, float* __restrict__ out)
{
    float acc = 0.0f;
    for (int i = threadIdx.x; i < NB; i += 1024) acc += partial[i];

    #pragma unroll
    for (int off = 32; off > 0; off >>= 1)
        acc += __shfl_down(acc, off, 64);

    __shared__ float wsum[16];
    const int lane = threadIdx.x & 63;
    const int wid  = threadIdx.x >> 6;
    if (lane == 0) wsum[wid] = acc;
    __syncthreads();
    if (wid == 0) {
        float v = (lane < 16) ? wsum[lane] : 0.0f;
        #pragma unroll
        for (int off = 8; off > 0; off >>= 1)
            v += __shfl_down(v, off, 64);
        if (lane == 0) out[0] = v * (1.0f / 16.0f);
    }
}

extern "C" void kernel_launch(void* const* d_in, const int* in_sizes, int n_in,
                              void* d_out, int out_size, void* d_ws, size_t ws_size,
                              hipStream_t stream) {
    const float* src = (const float*)d_in[0];
    const float* tgt = (const float*)d_in[1];
    float* out = (float*)d_out;

    if (ws_size >= (size_t)NB * sizeof(float)) {
        float* partial = (float*)d_ws;
        sobel_partial_kernel<false><<<dim3(NB), dim3(256), 0, stream>>>(src, tgt, partial);
        reduce_kernel<<<dim3(1), dim3(1024), 0, stream>>>(partial, out);
    } else {
        hipMemsetAsync(out, 0, (size_t)out_size * sizeof(float), stream);
        sobel_partial_kernel<true><<<dim3(NB), dim3(256), 0, stream>>>(src, tgt, out);
    }
}